// Round 1
// baseline (1332.414 us; speedup 1.0000x reference)
//
#include <hip/hip_runtime.h>
#include <hip/hip_bf16.h>
#include <math.h>

// Problem constants
#define BB 8
#define CC 256
#define NN 4096
#define C8 32

// ---------------------------------------------------------------------------
// Kernel 0: concatenate weights into WcatT[c][320] (transposed for coalesced
// per-output-lane loads) and bcat[320].
// Output order o: [0,32) = q rows, [32,64) = k rows, [64,320) = v rows.
// ---------------------------------------------------------------------------
__global__ void prep_w_kernel(const float* __restrict__ Wq, const float* __restrict__ bq,
                              const float* __restrict__ Wk, const float* __restrict__ bk,
                              const float* __restrict__ Wv, const float* __restrict__ bv,
                              float* __restrict__ WcatT, float* __restrict__ bcat) {
    int idx = blockIdx.x * 256 + threadIdx.x;
    if (idx < 320) {
        bcat[idx] = (idx < 32) ? bq[idx] : (idx < 64 ? bk[idx - 32] : bv[idx - 64]);
    }
    if (idx < 320 * 256) {
        int o = idx >> 8;
        int c = idx & 255;
        float v = (o < 32) ? Wq[o * 256 + c]
                           : (o < 64 ? Wk[(o - 32) * 256 + c] : Wv[(o - 64) * 256 + c]);
        WcatT[c * 320 + o] = v;
    }
}

// ---------------------------------------------------------------------------
// Kernel 1: QKV projection.
//   qT[b][i][d] (d<32), kT[b][i][d], vT[b][i][c] (c<256)
// Block = 256 threads, handles one (b, 64-position tile).
// Thread t: to = t&63 (output-channel lane), tp = t>>6 (position group).
// Each thread: 5 outputs (to + 64*uo) x 16 positions (tp + 4*pi).
// ---------------------------------------------------------------------------
__global__ __launch_bounds__(256) void qkv_kernel(
    const float* __restrict__ x, const float* __restrict__ WcatT,
    const float* __restrict__ bcat,
    float* __restrict__ qT, float* __restrict__ kT, float* __restrict__ vT) {
    // stage1: xs[c][ii] (c-major, 256x64 = 16384 floats)
    // stage2 (reuse): v-transpose staging [64][258] = 16512 floats
    __shared__ float xs[16512];
    __shared__ float qks[64 * 66];  // q/k transpose staging, pad 66

    int blk = blockIdx.x;
    int b = blk >> 6;
    int i0 = (blk & 63) << 6;
    int t = threadIdx.x;

    const float* xb = x + ((size_t)b << 20);  // b*C*N
    for (int idx = t; idx < 256 * 64; idx += 256) {
        int c = idx >> 6, ii = idx & 63;
        xs[idx] = xb[((size_t)c << 12) + i0 + ii];
    }
    __syncthreads();

    int to = t & 63;
    int tp = t >> 6;  // wave-uniform (0..3)

    float acc[80];
#pragma unroll
    for (int uo = 0; uo < 5; ++uo) {
        float bias = bcat[to + 64 * uo];
#pragma unroll
        for (int pi = 0; pi < 16; ++pi) acc[uo * 16 + pi] = bias;
    }

    for (int c = 0; c < 256; ++c) {
        const float* wc = WcatT + c * 320 + to;
        float w0 = wc[0];
        float w1 = wc[64];
        float w2 = wc[128];
        float w3 = wc[192];
        float w4 = wc[256];
#pragma unroll
        for (int pi = 0; pi < 16; ++pi) {
            float xv = xs[c * 64 + tp + 4 * pi];  // wave-uniform broadcast read
            acc[0 * 16 + pi] += w0 * xv;
            acc[1 * 16 + pi] += w1 * xv;
            acc[2 * 16 + pi] += w2 * xv;
            acc[3 * 16 + pi] += w3 * xv;
            acc[4 * 16 + pi] += w4 * xv;
        }
    }
    __syncthreads();  // done reading xs stage1

    // stage2: scatter into LDS transpose buffers
#pragma unroll
    for (int uo = 0; uo < 5; ++uo) {
        int o = to + 64 * uo;
#pragma unroll
        for (int pi = 0; pi < 16; ++pi) {
            int ii = tp + 4 * pi;
            float v = acc[uo * 16 + pi];
            if (o < 64) qks[ii * 66 + o] = v;          // uo==0 only
            else        xs[ii * 258 + (o - 64)] = v;   // v channels
        }
    }
    __syncthreads();

    // coalesced copy-out
    float* qTb = qT + ((size_t)b << 17) + (size_t)i0 * 32;
    float* kTb = kT + ((size_t)b << 17) + (size_t)i0 * 32;
    for (int idx = t; idx < 64 * 32; idx += 256) {
        int ii = idx >> 5, d = idx & 31;
        qTb[idx] = qks[ii * 66 + d];
        kTb[idx] = qks[ii * 66 + 32 + d];
    }
    float* vTb = vT + ((size_t)b << 20) + (size_t)i0 * 256;
    for (int idx = t; idx < 64 * 256; idx += 256) {
        int ii = idx >> 8, c = idx & 255;
        vTb[idx] = xs[ii * 258 + c];
    }
}

// ---------------------------------------------------------------------------
// Kernel 2: flash attention + residual.
// Block = 256 threads (4 waves), QB=64 queries, JB=32 key chunk.
// Score phase: wave wid owns queries [16*wid, 16*wid+16); lane = iqL*4 + s;
//   each lane computes 8 scores (j = s*8+jj), online softmax over 4-lane group.
// PV phase: thread (tq = t&15, tc = t>>4): 4 queries (tq+16*qq) x 16 channels
//   (granule-interleaved: c = 4*(tc+16*w4)+e) register tile.
// ---------------------------------------------------------------------------
__global__ __launch_bounds__(256) void attn_kernel(
    const float* __restrict__ qT, const float* __restrict__ kT,
    const float* __restrict__ vT, const float* __restrict__ x,
    const float* __restrict__ gamma, float* __restrict__ out) {
    __shared__ float k_s[32 * 36];   // pad 36
    __shared__ float v_s[32 * 256];  // [jj][c]
    __shared__ float p_s[64 * 36];   // [iq][jj], pad 36
    __shared__ float scale_s[64];
    __shared__ float l_s[64];

    int blk = blockIdx.x;
    int b = blk >> 6;
    int i0 = (blk & 63) << 6;
    int t = threadIdx.x;
    int lane = t & 63;
    int wid = t >> 6;

    // score-phase identity
    int iqL = lane >> 2;
    int s = lane & 3;
    int iq = wid * 16 + iqL;

    // PV identity
    int tq = t & 15;
    int tc = t >> 4;

    // preload this thread's query row (32 floats)
    float4 qreg[8];
    {
        const float4* qrow =
            (const float4*)(qT + ((size_t)b << 17) + (size_t)(i0 + iq) * 32);
#pragma unroll
        for (int d4 = 0; d4 < 8; ++d4) qreg[d4] = qrow[d4];
    }

    float m = -INFINITY, l = 0.f;
    float4 acc[4][4];
#pragma unroll
    for (int qq = 0; qq < 4; ++qq)
#pragma unroll
        for (int w4 = 0; w4 < 4; ++w4) acc[qq][w4] = make_float4(0.f, 0.f, 0.f, 0.f);

    const float* kTb = kT + ((size_t)b << 17);
    const float* vTb = vT + ((size_t)b << 20);

    for (int j0 = 0; j0 < NN; j0 += 32) {
        __syncthreads();  // protect k_s/v_s/p_s from prior-iteration readers
        // stage K chunk (32 x 32, pad 36)
        {
            int idx = t;  // 256 threads, 256 float4s
            int jj = idx >> 3, d4 = idx & 7;
            float4 kv = ((const float4*)(kTb + (size_t)(j0 + jj) * 32))[d4];
            ((float4*)(k_s + jj * 36))[d4] = kv;
        }
        // stage V chunk (32 x 256)
        {
            const float4* v4 = (const float4*)(vTb + (size_t)j0 * 256);
            float4* vs4 = (float4*)v_s;
            for (int idx = t; idx < 32 * 64; idx += 256) vs4[idx] = v4[idx];
        }
        __syncthreads();

        // ---- scores + online softmax ----
        float p[8];
        float cmax = -INFINITY;
#pragma unroll
        for (int jj = 0; jj < 8; ++jj) {
            int j = s * 8 + jj;
            const float4* krow = (const float4*)(k_s + j * 36);
            float dot = 0.f;
#pragma unroll
            for (int d4 = 0; d4 < 8; ++d4) {
                float4 kv = krow[d4];
                dot += qreg[d4].x * kv.x + qreg[d4].y * kv.y + qreg[d4].z * kv.z +
                       qreg[d4].w * kv.w;
            }
            p[jj] = dot;
            cmax = fmaxf(cmax, dot);
        }
        cmax = fmaxf(cmax, __shfl_xor(cmax, 1));
        cmax = fmaxf(cmax, __shfl_xor(cmax, 2));
        float m_new = fmaxf(m, cmax);
        float scale = __expf(m - m_new);
        float psum = 0.f;
#pragma unroll
        for (int jj = 0; jj < 8; ++jj) {
            p[jj] = __expf(p[jj] - m_new);
            psum += p[jj];
        }
        psum += __shfl_xor(psum, 1);
        psum += __shfl_xor(psum, 2);
        l = l * scale + psum;
        m = m_new;
#pragma unroll
        for (int jj = 0; jj < 8; ++jj) p_s[iq * 36 + s * 8 + jj] = p[jj];
        if (s == 0) {
            scale_s[iq] = scale;
            l_s[iq] = l;
        }
        __syncthreads();

        // ---- PV accumulate ----
        float sc0 = scale_s[tq];
        float sc1 = scale_s[tq + 16];
        float sc2 = scale_s[tq + 32];
        float sc3 = scale_s[tq + 48];
#pragma unroll
        for (int w4 = 0; w4 < 4; ++w4) {
            acc[0][w4].x *= sc0; acc[0][w4].y *= sc0; acc[0][w4].z *= sc0; acc[0][w4].w *= sc0;
            acc[1][w4].x *= sc1; acc[1][w4].y *= sc1; acc[1][w4].z *= sc1; acc[1][w4].w *= sc1;
            acc[2][w4].x *= sc2; acc[2][w4].y *= sc2; acc[2][w4].z *= sc2; acc[2][w4].w *= sc2;
            acc[3][w4].x *= sc3; acc[3][w4].y *= sc3; acc[3][w4].z *= sc3; acc[3][w4].w *= sc3;
        }
#pragma unroll 4
        for (int jj = 0; jj < 32; ++jj) {
            float p0 = p_s[tq * 36 + jj];
            float p1 = p_s[(tq + 16) * 36 + jj];
            float p2 = p_s[(tq + 32) * 36 + jj];
            float p3 = p_s[(tq + 48) * 36 + jj];
            const float4* vrow = (const float4*)(v_s + jj * 256);
#pragma unroll
            for (int w4 = 0; w4 < 4; ++w4) {
                float4 vv = vrow[tc + 16 * w4];
                acc[0][w4].x += p0 * vv.x; acc[0][w4].y += p0 * vv.y;
                acc[0][w4].z += p0 * vv.z; acc[0][w4].w += p0 * vv.w;
                acc[1][w4].x += p1 * vv.x; acc[1][w4].y += p1 * vv.y;
                acc[1][w4].z += p1 * vv.z; acc[1][w4].w += p1 * vv.w;
                acc[2][w4].x += p2 * vv.x; acc[2][w4].y += p2 * vv.y;
                acc[2][w4].z += p2 * vv.z; acc[2][w4].w += p2 * vv.w;
                acc[3][w4].x += p3 * vv.x; acc[3][w4].y += p3 * vv.y;
                acc[3][w4].z += p3 * vv.z; acc[3][w4].w += p3 * vv.w;
            }
        }
    }

    // ---- epilogue: out = gamma*(acc/l) + x ----
    float rl[4];
    rl[0] = 1.f / l_s[tq];
    rl[1] = 1.f / l_s[tq + 16];
    rl[2] = 1.f / l_s[tq + 32];
    rl[3] = 1.f / l_s[tq + 48];
    const float* xb = x + ((size_t)b << 20);
    float* ob = out + ((size_t)b << 20);
    float g = gamma[0];
#pragma unroll
    for (int qq = 0; qq < 4; ++qq) {
        int i = i0 + tq + 16 * qq;
        float r = rl[qq];
#pragma unroll
        for (int w4 = 0; w4 < 4; ++w4) {
            int cbase = 4 * (tc + 16 * w4);
            size_t base = (size_t)cbase * NN + i;
            ob[base]            = g * (acc[qq][w4].x * r) + xb[base];
            ob[base + NN]       = g * (acc[qq][w4].y * r) + xb[base + NN];
            ob[base + 2 * NN]   = g * (acc[qq][w4].z * r) + xb[base + 2 * NN];
            ob[base + 3 * NN]   = g * (acc[qq][w4].w * r) + xb[base + 3 * NN];
        }
    }
}

// ---------------------------------------------------------------------------
extern "C" void kernel_launch(void* const* d_in, const int* in_sizes, int n_in,
                              void* d_out, int out_size, void* d_ws, size_t ws_size,
                              hipStream_t stream) {
    const float* x = (const float*)d_in[0];
    const float* Wq = (const float*)d_in[1];
    const float* bq = (const float*)d_in[2];
    const float* Wk = (const float*)d_in[3];
    const float* bk = (const float*)d_in[4];
    const float* Wv = (const float*)d_in[5];
    const float* bv = (const float*)d_in[6];
    const float* gamma = (const float*)d_in[7];
    float* out = (float*)d_out;

    // workspace layout (floats): qT | kT | vT | WcatT | bcat  (~40.3 MB)
    float* ws = (float*)d_ws;
    float* qTw = ws;                      // 8*4096*32   = 1,048,576
    float* kTw = ws + 1048576;            // 1,048,576
    float* vTw = ws + 2097152;            // 8*4096*256  = 8,388,608
    float* WcatT = ws + 10485760;         // 256*320     = 81,920
    float* bcat = ws + 10567680;          // 320

    prep_w_kernel<<<320, 256, 0, stream>>>(Wq, bq, Wk, bk, Wv, bv, WcatT, bcat);
    qkv_kernel<<<BB * (NN / 64), 256, 0, stream>>>(x, WcatT, bcat, qTw, kTw, vTw);
    attn_kernel<<<BB * (NN / 64), 256, 0, stream>>>(qTw, kTw, vTw, x, gamma, out);
}

// Round 2
// 293.316 us; speedup vs baseline: 4.5426x; 4.5426x over previous
//
#include <hip/hip_runtime.h>
#include <math.h>

#define BB 8
#define CC 256
#define NN 4096

typedef float f4 __attribute__((ext_vector_type(4)));
typedef short bh8 __attribute__((ext_vector_type(8)));

__device__ __forceinline__ unsigned short f2bf(float f) {
    unsigned u = __builtin_bit_cast(unsigned, f);
    u += 0x7fff + ((u >> 16) & 1);
    return (unsigned short)(u >> 16);
}

// ---------------------------------------------------------------------------
// Kernel 0: concatenate weights into WcatT[c][320] + bcat[320] (fp32).
// Output order o: [0,32) q rows, [32,64) k rows, [64,320) v rows.
// ---------------------------------------------------------------------------
__global__ void prep_w_kernel(const float* __restrict__ Wq, const float* __restrict__ bq,
                              const float* __restrict__ Wk, const float* __restrict__ bk,
                              const float* __restrict__ Wv, const float* __restrict__ bv,
                              float* __restrict__ WcatT, float* __restrict__ bcat) {
    int idx = blockIdx.x * 256 + threadIdx.x;
    if (idx < 320) {
        bcat[idx] = (idx < 32) ? bq[idx] : (idx < 64 ? bk[idx - 32] : bv[idx - 64]);
    }
    if (idx < 320 * 256) {
        int o = idx >> 8;
        int c = idx & 255;
        float v = (o < 32) ? Wq[o * 256 + c]
                           : (o < 64 ? Wk[(o - 32) * 256 + c] : Wv[(o - 64) * 256 + c]);
        WcatT[c * 320 + o] = v;
    }
}

// ---------------------------------------------------------------------------
// Kernel 1: QKV projection (fp32 math), bf16 outputs:
//   q64[b][i][64] u16 : cols 0..31 = q_hi, 32..63 = q_lo   (split bf16)
//   k64[b][i][64] u16 : same for k
//   vC [b][c][n]  bf16 : channel-major
// Block = 256 threads, one (b, 64-position tile).
// ---------------------------------------------------------------------------
__global__ __launch_bounds__(256) void qkv_kernel(
    const float* __restrict__ x, const float* __restrict__ WcatT,
    const float* __restrict__ bcat,
    unsigned short* __restrict__ q64, unsigned short* __restrict__ k64,
    unsigned short* __restrict__ vC) {
    __shared__ float xs[256 * 64];               // 64KB; reused as vsl after compute
    __shared__ unsigned short qkl[64 * 128];     // 16KB
    unsigned short* vsl = (unsigned short*)xs;   // [256][66] u16 overlay

    int blk = blockIdx.x;
    int b = blk >> 6;
    int i0 = (blk & 63) << 6;
    int t = threadIdx.x;

    const float* xb = x + ((size_t)b << 20);
    for (int idx = t; idx < 256 * 64; idx += 256) {
        int c = idx >> 6, ii = idx & 63;
        xs[idx] = xb[((size_t)c << 12) + i0 + ii];
    }
    __syncthreads();

    int to = t & 63;
    int tp = t >> 6;  // wave-uniform

    float acc[80];
#pragma unroll
    for (int uo = 0; uo < 5; ++uo) {
        float bias = bcat[to + 64 * uo];
#pragma unroll
        for (int pi = 0; pi < 16; ++pi) acc[uo * 16 + pi] = bias;
    }

    for (int c = 0; c < 256; ++c) {
        const float* wc = WcatT + c * 320 + to;
        float w0 = wc[0];
        float w1 = wc[64];
        float w2 = wc[128];
        float w3 = wc[192];
        float w4 = wc[256];
#pragma unroll
        for (int pi = 0; pi < 16; ++pi) {
            float xv = xs[c * 64 + tp + 4 * pi];
            acc[0 * 16 + pi] += w0 * xv;
            acc[1 * 16 + pi] += w1 * xv;
            acc[2 * 16 + pi] += w2 * xv;
            acc[3 * 16 + pi] += w3 * xv;
            acc[4 * 16 + pi] += w4 * xv;
        }
    }
    __syncthreads();  // done reading xs; safe to overlay vsl

    // q/k staging: hi/lo split bf16
#pragma unroll
    for (int pi = 0; pi < 16; ++pi) {
        int ii = tp + 4 * pi;
        float v = acc[pi];  // uo == 0
        unsigned short hi = f2bf(v);
        float vhi = __builtin_bit_cast(float, ((unsigned)hi) << 16);
        unsigned short lo = f2bf(v - vhi);
        if (to < 32) {
            qkl[ii * 128 + to] = hi;
            qkl[ii * 128 + 32 + to] = lo;
        } else {
            qkl[ii * 128 + 32 + to] = hi;  // 64 + (to-32)
            qkl[ii * 128 + 64 + to] = lo;  // 96 + (to-32)
        }
    }
    // v staging: channel-major bf16, pad 66
#pragma unroll
    for (int uo = 1; uo < 5; ++uo) {
#pragma unroll
        for (int pi = 0; pi < 16; ++pi) {
            int c = to + 64 * (uo - 1);
            int ii = tp + 4 * pi;
            vsl[c * 66 + ii] = f2bf(acc[uo * 16 + pi]);
        }
    }
    __syncthreads();

    // coalesced copy-out
    const unsigned* qk32 = (const unsigned*)qkl;
    unsigned* qb = (unsigned*)(q64 + ((size_t)(b * NN + i0)) * 64);
    unsigned* kb = (unsigned*)(k64 + ((size_t)(b * NN + i0)) * 64);
    for (int idx = t; idx < 64 * 32; idx += 256) {
        int row = idx >> 5, dw = idx & 31;
        qb[row * 32 + dw] = qk32[row * 64 + dw];
        kb[row * 32 + dw] = qk32[row * 64 + 32 + dw];
    }
    for (int idx = t; idx < 256 * 32; idx += 256) {
        int c = idx >> 5, dw = idx & 31;
        unsigned val = *(const unsigned*)(vsl + c * 66 + 2 * dw);
        *(unsigned*)(vC + ((size_t)(b * CC + c)) * NN + i0 + 2 * dw) = val;
    }
}

// ---------------------------------------------------------------------------
// Kernel 2: MFMA flash attention + residual.
// Block = 256 threads (4 waves), 128 queries/block (32/wave, R=2), chunk = 64 keys.
// S^T = mfma(A=K, B=Q): lane holds col i = lane&15, rows j = 16jt+4g+reg.
// out^T = mfma(A=V^T from LDS, B=P^T from shfl): col i, rows c.
// V staged channel-major [256][64] bf16 in LDS, XOR-swizzled 16B slots,
// double-buffered, via global_load_lds (linear dest + pre-swizzled source).
// ---------------------------------------------------------------------------
__global__ __launch_bounds__(256, 1) void attn_kernel(
    const unsigned short* __restrict__ q64, const unsigned short* __restrict__ k64,
    const unsigned short* __restrict__ vC, const float* __restrict__ x,
    const float* __restrict__ gamma, float* __restrict__ out) {
    __shared__ unsigned short vs[2][256 * 64];  // 64KB double-buffered V

    int t = threadIdx.x;
    int lane = t & 63;
    int w = t >> 6;
    int g = lane >> 4;
    int li = lane & 15;
    int blk = blockIdx.x;
    int b = blk & 7;              // XCD-affine batch mapping
    int i0 = (blk >> 3) << 7;     // 128-query tile
    int qb = i0 + 32 * w;         // wave's query base

    const unsigned short* vb = vC + ((size_t)b * CC) * NN;
    const unsigned short* kb = k64 + ((size_t)b * NN) * 64;

    // Q fragments (resident): [r][hi/lo]
    bh8 qf[2][2];
#pragma unroll
    for (int r = 0; r < 2; ++r)
#pragma unroll
        for (int s = 0; s < 2; ++s)
            qf[r][s] = *(const bh8*)(q64 + ((size_t)(b * NN + qb + 16 * r + li)) * 64 + s * 32 + 8 * g);

    f4 acc[16][2];
#pragma unroll
    for (int ct = 0; ct < 16; ++ct)
#pragma unroll
        for (int r = 0; r < 2; ++r) acc[ct][r] = (f4){0.f, 0.f, 0.f, 0.f};
    float m[2] = {-INFINITY, -INFINITY};
    float l[2] = {0.f, 0.f};

    auto stageV = [&](int buf, int j0) {
#pragma unroll
        for (int s = 0; s < 8; ++s) {
            int c = 64 * w + 8 * s + (lane >> 3);
            int slot = (lane & 7) ^ (c & 7);
            const unsigned short* src = vb + (size_t)c * NN + j0 + slot * 8;
            __builtin_amdgcn_global_load_lds(
                (const __attribute__((address_space(1))) unsigned int*)src,
                (__attribute__((address_space(3))) unsigned int*)(&vs[buf][(64 * w + 8 * s) * 64]),
                16, 0, 0);
        }
    };
    auto loadK = [&](bh8 kf[4][2], int j0) {
#pragma unroll
        for (int jt = 0; jt < 4; ++jt)
#pragma unroll
            for (int s = 0; s < 2; ++s)
                kf[jt][s] = *(const bh8*)(kb + (size_t)(j0 + 16 * jt + li) * 64 + s * 32 + 8 * g);
    };

    bh8 kfA[4][2], kfB[4][2];
    stageV(0, 0);
    loadK(kfA, 0);
    __syncthreads();

    for (int tt = 0; tt < 64; ++tt) {
        int cur = tt & 1;
        if (tt < 63) {
            stageV(cur ^ 1, (tt + 1) << 6);
            loadK(kfB, (tt + 1) << 6);
        }

        // ---- QK^T (swapped, 3-product bf16 split => ~fp32 scores) ----
        f4 sacc[4][2];
#pragma unroll
        for (int jt = 0; jt < 4; ++jt)
#pragma unroll
            for (int r = 0; r < 2; ++r) {
                f4 a = {0.f, 0.f, 0.f, 0.f};
                a = __builtin_amdgcn_mfma_f32_16x16x32_bf16(kfA[jt][0], qf[r][0], a, 0, 0, 0);
                a = __builtin_amdgcn_mfma_f32_16x16x32_bf16(kfA[jt][1], qf[r][0], a, 0, 0, 0);
                a = __builtin_amdgcn_mfma_f32_16x16x32_bf16(kfA[jt][0], qf[r][1], a, 0, 0, 0);
                sacc[jt][r] = a;
            }

        // ---- online softmax (per lane: one query column per r) ----
        float scl[2];
#pragma unroll
        for (int r = 0; r < 2; ++r) {
            float mx = sacc[0][r][0];
#pragma unroll
            for (int jt = 0; jt < 4; ++jt)
#pragma unroll
                for (int e = 0; e < 4; ++e) mx = fmaxf(mx, sacc[jt][r][e]);
            mx = fmaxf(mx, __shfl_xor(mx, 16));
            mx = fmaxf(mx, __shfl_xor(mx, 32));
            float mnew = fmaxf(m[r], mx);
            float sc = __expf(m[r] - mnew);
            m[r] = mnew;
            float sum = 0.f;
#pragma unroll
            for (int jt = 0; jt < 4; ++jt)
#pragma unroll
                for (int e = 0; e < 4; ++e) {
                    float p = __expf(sacc[jt][r][e] - mnew);
                    sacc[jt][r][e] = p;
                    sum += p;
                }
            sum += __shfl_xor(sum, 16);
            sum += __shfl_xor(sum, 32);
            l[r] = l[r] * sc + sum;
            scl[r] = sc;
        }
#pragma unroll
        for (int ct = 0; ct < 16; ++ct)
#pragma unroll
            for (int r = 0; r < 2; ++r)
#pragma unroll
                for (int e = 0; e < 4; ++e) acc[ct][r][e] *= scl[r];

        // ---- P^T fragments (in-register shfl redistribution) + PV ----
        const char* vsb = (const char*)vs[cur];
#pragma unroll
        for (int h = 0; h < 2; ++h) {
            bh8 pb[2];
#pragma unroll
            for (int r = 0; r < 2; ++r) {
                unsigned pk[2][2];
#pragma unroll
                for (int tl = 0; tl < 2; ++tl)
#pragma unroll
                    for (int pp = 0; pp < 2; ++pp) {
                        unsigned lo16 = f2bf(sacc[2 * h + tl][r][2 * pp]);
                        unsigned hi16 = f2bf(sacc[2 * h + tl][r][2 * pp + 1]);
                        pk[tl][pp] = lo16 | (hi16 << 16);
                    }
                union { unsigned u[4]; bh8 v; } un;
#pragma unroll
                for (int d = 0; d < 4; ++d) {
                    int srcl = (((2 * g + (d >> 1)) & 3) << 4) | li;
                    unsigned a0 = (unsigned)__shfl((int)pk[0][d & 1], srcl);
                    unsigned a1 = (unsigned)__shfl((int)pk[1][d & 1], srcl);
                    un.u[d] = (g >> 1) ? a1 : a0;
                }
                pb[r] = un.v;
            }
#pragma unroll
            for (int ct = 0; ct < 16; ++ct) {
                int c = 16 * ct + li;
                int off = c * 128 + ((64 * h + 16 * g) ^ ((c & 7) << 4));
                bh8 vf = *(const bh8*)(vsb + off);
                acc[ct][0] = __builtin_amdgcn_mfma_f32_16x16x32_bf16(vf, pb[0], acc[ct][0], 0, 0, 0);
                acc[ct][1] = __builtin_amdgcn_mfma_f32_16x16x32_bf16(vf, pb[1], acc[ct][1], 0, 0, 0);
            }
        }
        __syncthreads();
        if (tt < 63) {
#pragma unroll
            for (int jt = 0; jt < 4; ++jt)
#pragma unroll
                for (int s = 0; s < 2; ++s) kfA[jt][s] = kfB[jt][s];
        }
    }

    // ---- epilogue: out = gamma*(acc/l) + x ----
    float gm = gamma[0];
    float rl[2] = {1.f / l[0], 1.f / l[1]};
    const float* xb = x + ((size_t)b * CC) * NN;
    float* ob = out + ((size_t)b * CC) * NN;
#pragma unroll
    for (int ct = 0; ct < 16; ++ct)
#pragma unroll
        for (int r = 0; r < 2; ++r) {
            int i = qb + 16 * r + li;
#pragma unroll
            for (int e = 0; e < 4; ++e) {
                int c = 16 * ct + 4 * g + e;
                size_t idx = (size_t)c * NN + i;
                ob[idx] = gm * (acc[ct][r][e] * rl[r]) + xb[idx];
            }
        }
}

// ---------------------------------------------------------------------------
extern "C" void kernel_launch(void* const* d_in, const int* in_sizes, int n_in,
                              void* d_out, int out_size, void* d_ws, size_t ws_size,
                              hipStream_t stream) {
    const float* x = (const float*)d_in[0];
    const float* Wq = (const float*)d_in[1];
    const float* bq = (const float*)d_in[2];
    const float* Wk = (const float*)d_in[3];
    const float* bk = (const float*)d_in[4];
    const float* Wv = (const float*)d_in[5];
    const float* bv = (const float*)d_in[6];
    const float* gamma = (const float*)d_in[7];
    float* out = (float*)d_out;

    // workspace layout (bytes):
    // q64 @0 (4MB) | k64 @4MB (4MB) | vC @8MB (16MB) | WcatT @24MB | bcat
    unsigned short* ws16 = (unsigned short*)d_ws;
    unsigned short* q64w = ws16;
    unsigned short* k64w = ws16 + 2097152;
    unsigned short* vCw = ws16 + 4194304;
    float* WcatT = (float*)((char*)d_ws + 25165824);
    float* bcat = WcatT + 81920;

    prep_w_kernel<<<320, 256, 0, stream>>>(Wq, bq, Wk, bk, Wv, bv, WcatT, bcat);
    qkv_kernel<<<BB * (NN / 64), 256, 0, stream>>>(x, WcatT, bcat, q64w, k64w, vCw);
    attn_kernel<<<256, 256, 0, stream>>>(q64w, k64w, vCw, x, gamma, out);
}

// Round 4
// 281.460 us; speedup vs baseline: 4.7339x; 1.0421x over previous
//
#include <hip/hip_runtime.h>
#include <math.h>

#define BB 8
#define CC 256
#define NN 4096

typedef float f4 __attribute__((ext_vector_type(4)));
typedef short bh8 __attribute__((ext_vector_type(8)));

__device__ __forceinline__ unsigned short f2bf(float f) {
    unsigned u = __builtin_bit_cast(unsigned, f);
    u += 0x7fff + ((u >> 16) & 1);
    return (unsigned short)(u >> 16);
}

// ---------------------------------------------------------------------------
// Kernel 0: concatenate weights into WcatT[c][320] + bcat[320] (fp32).
// ---------------------------------------------------------------------------
__global__ void prep_w_kernel(const float* __restrict__ Wq, const float* __restrict__ bq,
                              const float* __restrict__ Wk, const float* __restrict__ bk,
                              const float* __restrict__ Wv, const float* __restrict__ bv,
                              float* __restrict__ WcatT, float* __restrict__ bcat) {
    int idx = blockIdx.x * 256 + threadIdx.x;
    if (idx < 320) {
        bcat[idx] = (idx < 32) ? bq[idx] : (idx < 64 ? bk[idx - 32] : bv[idx - 64]);
    }
    if (idx < 320 * 256) {
        int o = idx >> 8;
        int c = idx & 255;
        float v = (o < 32) ? Wq[o * 256 + c]
                           : (o < 64 ? Wk[(o - 32) * 256 + c] : Wv[(o - 64) * 256 + c]);
        WcatT[c * 320 + o] = v;
    }
}

// ---------------------------------------------------------------------------
// Kernel 1: QKV projection (fp32 math), bf16 outputs (unchanged, proven).
// ---------------------------------------------------------------------------
__global__ __launch_bounds__(256) void qkv_kernel(
    const float* __restrict__ x, const float* __restrict__ WcatT,
    const float* __restrict__ bcat,
    unsigned short* __restrict__ q64, unsigned short* __restrict__ k64,
    unsigned short* __restrict__ vC) {
    __shared__ float xs[256 * 64];
    __shared__ unsigned short qkl[64 * 128];
    unsigned short* vsl = (unsigned short*)xs;  // [256][66] u16 overlay

    int blk = blockIdx.x;
    int b = blk >> 6;
    int i0 = (blk & 63) << 6;
    int t = threadIdx.x;

    const float* xb = x + ((size_t)b << 20);
    for (int idx = t; idx < 256 * 64; idx += 256) {
        int c = idx >> 6, ii = idx & 63;
        xs[idx] = xb[((size_t)c << 12) + i0 + ii];
    }
    __syncthreads();

    int to = t & 63;
    int tp = t >> 6;

    float acc[80];
#pragma unroll
    for (int uo = 0; uo < 5; ++uo) {
        float bias = bcat[to + 64 * uo];
#pragma unroll
        for (int pi = 0; pi < 16; ++pi) acc[uo * 16 + pi] = bias;
    }

    for (int c = 0; c < 256; ++c) {
        const float* wc = WcatT + c * 320 + to;
        float w0 = wc[0];
        float w1 = wc[64];
        float w2 = wc[128];
        float w3 = wc[192];
        float w4 = wc[256];
#pragma unroll
        for (int pi = 0; pi < 16; ++pi) {
            float xv = xs[c * 64 + tp + 4 * pi];
            acc[0 * 16 + pi] += w0 * xv;
            acc[1 * 16 + pi] += w1 * xv;
            acc[2 * 16 + pi] += w2 * xv;
            acc[3 * 16 + pi] += w3 * xv;
            acc[4 * 16 + pi] += w4 * xv;
        }
    }
    __syncthreads();

#pragma unroll
    for (int pi = 0; pi < 16; ++pi) {
        int ii = tp + 4 * pi;
        float v = acc[pi];
        unsigned short hi = f2bf(v);
        float vhi = __builtin_bit_cast(float, ((unsigned)hi) << 16);
        unsigned short lo = f2bf(v - vhi);
        if (to < 32) {
            qkl[ii * 128 + to] = hi;
            qkl[ii * 128 + 32 + to] = lo;
        } else {
            qkl[ii * 128 + 32 + to] = hi;
            qkl[ii * 128 + 64 + to] = lo;
        }
    }
#pragma unroll
    for (int uo = 1; uo < 5; ++uo) {
#pragma unroll
        for (int pi = 0; pi < 16; ++pi) {
            int c = to + 64 * (uo - 1);
            int ii = tp + 4 * pi;
            vsl[c * 66 + ii] = f2bf(acc[uo * 16 + pi]);
        }
    }
    __syncthreads();

    const unsigned* qk32 = (const unsigned*)qkl;
    unsigned* qb = (unsigned*)(q64 + ((size_t)(b * NN + i0)) * 64);
    unsigned* kb = (unsigned*)(k64 + ((size_t)(b * NN + i0)) * 64);
    for (int idx = t; idx < 64 * 32; idx += 256) {
        int row = idx >> 5, dw = idx & 31;
        qb[row * 32 + dw] = qk32[row * 64 + dw];
        kb[row * 32 + dw] = qk32[row * 64 + 32 + dw];
    }
    for (int idx = t; idx < 256 * 32; idx += 256) {
        int c = idx >> 5, dw = idx & 31;
        unsigned val = *(const unsigned*)(vsl + c * 66 + 2 * dw);
        *(unsigned*)(vC + ((size_t)(b * CC + c)) * NN + i0 + 2 * dw) = val;
    }
}

// ---------------------------------------------------------------------------
// Kernel 2: MFMA flash attention + residual. (R2-proven numerics, 2 blocks/CU)
// Grid 512 (8 batches x 64 tiles of 64 queries), 4 waves x 16 queries (R=1).
// QK: Sᵀ = mfma_16x16x32(A=K, B=Q), 3-product split-bf16 -> fp32-grade scores.
// PV: outᵀ = mfma_16x16x32(A=Vᵀ from LDS, B=Pᵀ via shfl redistribution).
// V channel-major [256][64] bf16 LDS, XOR-swizzled 16B slots, double-buffered.
// ---------------------------------------------------------------------------
__global__ __launch_bounds__(256, 2) void attn_kernel(
    const unsigned short* __restrict__ q64, const unsigned short* __restrict__ k64,
    const unsigned short* __restrict__ vC, const float* __restrict__ x,
    const float* __restrict__ gamma, float* __restrict__ out) {
    __shared__ unsigned short vs[2][256 * 64];  // 64KB double-buffered V

    int t = threadIdx.x;
    int lane = t & 63;
    int w = t >> 6;
    int g = lane >> 4;
    int li = lane & 15;
    int blk = blockIdx.x;
    int b = blk & 7;            // XCD-affine batch mapping
    int i0 = (blk >> 3) << 6;   // 64-query tile
    int qb = i0 + 16 * w;       // wave's query base (16 queries)

    const unsigned short* vb = vC + ((size_t)b * CC) * NN;
    const unsigned short* kb = k64 + ((size_t)b * NN) * 64;

    // Q fragments (resident): [hi/lo]
    bh8 qf[2];
#pragma unroll
    for (int s = 0; s < 2; ++s)
        qf[s] = *(const bh8*)(q64 + ((size_t)(b * NN + qb + li)) * 64 + s * 32 + 8 * g);

    f4 acc[16];
#pragma unroll
    for (int ct = 0; ct < 16; ++ct) acc[ct] = (f4){0.f, 0.f, 0.f, 0.f};
    float m = -INFINITY, l = 0.f;

    auto stageV = [&](int buf, int j0) {
#pragma unroll
        for (int s = 0; s < 8; ++s) {
            int c = 64 * w + 8 * s + (lane >> 3);
            int slot = (lane & 7) ^ (c & 7);
            const unsigned short* src = vb + (size_t)c * NN + j0 + slot * 8;
            __builtin_amdgcn_global_load_lds(
                (const __attribute__((address_space(1))) unsigned int*)src,
                (__attribute__((address_space(3))) unsigned int*)(&vs[buf][(64 * w + 8 * s) * 64]),
                16, 0, 0);
        }
    };
    auto loadK = [&](bh8 (&kf)[4][2], int j0) {
#pragma unroll
        for (int jt = 0; jt < 4; ++jt)
#pragma unroll
            for (int s = 0; s < 2; ++s)
                kf[jt][s] = *(const bh8*)(kb + (size_t)(j0 + 16 * jt + li) * 64 + s * 32 + 8 * g);
    };

    bh8 kfA[4][2], kfB[4][2];
    stageV(0, 0);
    loadK(kfA, 0);
    __syncthreads();

    auto step = [&](int tt, bh8 (&kc)[4][2], bh8 (&kn)[4][2], int buf) {
        if (tt < 63) {
            stageV(buf ^ 1, (tt + 1) << 6);
            loadK(kn, (tt + 1) << 6);
        }

        // ---- QK^T (swapped, 3-product bf16 split) ----
        f4 sacc[4];
#pragma unroll
        for (int jt = 0; jt < 4; ++jt) {
            f4 a = {0.f, 0.f, 0.f, 0.f};
            a = __builtin_amdgcn_mfma_f32_16x16x32_bf16(kc[jt][0], qf[0], a, 0, 0, 0);
            a = __builtin_amdgcn_mfma_f32_16x16x32_bf16(kc[jt][1], qf[0], a, 0, 0, 0);
            a = __builtin_amdgcn_mfma_f32_16x16x32_bf16(kc[jt][0], qf[1], a, 0, 0, 0);
            sacc[jt] = a;
        }

        // ---- online softmax (full rescale, R2-proven) ----
        float mx = sacc[0][0];
#pragma unroll
        for (int jt = 0; jt < 4; ++jt)
#pragma unroll
            for (int e = 0; e < 4; ++e) mx = fmaxf(mx, sacc[jt][e]);
        mx = fmaxf(mx, __shfl_xor(mx, 16));
        mx = fmaxf(mx, __shfl_xor(mx, 32));
        float mnew = fmaxf(m, mx);
        float sc = __expf(m - mnew);
        m = mnew;
        float sum = 0.f;
#pragma unroll
        for (int jt = 0; jt < 4; ++jt)
#pragma unroll
            for (int e = 0; e < 4; ++e) {
                float p = __expf(sacc[jt][e] - mnew);
                sacc[jt][e] = p;
                sum += p;
            }
        sum += __shfl_xor(sum, 16);
        sum += __shfl_xor(sum, 32);
        l = l * sc + sum;
#pragma unroll
        for (int ct = 0; ct < 16; ++ct)
#pragma unroll
            for (int e = 0; e < 4; ++e) acc[ct][e] *= sc;

        // ---- P^T fragments (in-register shfl redistribution) + PV ----
        const char* vsb = (const char*)vs[buf];
#pragma unroll
        for (int h = 0; h < 2; ++h) {
            bh8 pb;
            {
                unsigned pk[2][2];
#pragma unroll
                for (int tl = 0; tl < 2; ++tl)
#pragma unroll
                    for (int pp = 0; pp < 2; ++pp) {
                        unsigned lo16 = f2bf(sacc[2 * h + tl][2 * pp]);
                        unsigned hi16 = f2bf(sacc[2 * h + tl][2 * pp + 1]);
                        pk[tl][pp] = lo16 | (hi16 << 16);
                    }
                union { unsigned u[4]; bh8 v; } un;
#pragma unroll
                for (int d = 0; d < 4; ++d) {
                    int srcl = (((2 * g + (d >> 1)) & 3) << 4) | li;
                    unsigned a0 = (unsigned)__shfl((int)pk[0][d & 1], srcl);
                    unsigned a1 = (unsigned)__shfl((int)pk[1][d & 1], srcl);
                    un.u[d] = (g >> 1) ? a1 : a0;
                }
                pb = un.v;
            }
            __builtin_amdgcn_s_setprio(1);
#pragma unroll
            for (int ct = 0; ct < 16; ++ct) {
                int c = 16 * ct + li;
                int off = c * 128 + ((64 * h + 16 * g) ^ ((c & 7) << 4));
                bh8 vf = *(const bh8*)(vsb + off);
                acc[ct] = __builtin_amdgcn_mfma_f32_16x16x32_bf16(vf, pb, acc[ct], 0, 0, 0);
            }
            __builtin_amdgcn_s_setprio(0);
        }
        __syncthreads();
    };

    for (int tt = 0; tt < 64; tt += 2) {
        step(tt, kfA, kfB, 0);
        step(tt + 1, kfB, kfA, 1);
    }

    // ---- epilogue: out = gamma*(acc/l) + x ----
    float gm = gamma[0];
    float rl = 1.f / l;
    const float* xb = x + ((size_t)b * CC) * NN;
    float* ob = out + ((size_t)b * CC) * NN;
    int i = qb + li;
#pragma unroll
    for (int ct = 0; ct < 16; ++ct)
#pragma unroll
        for (int e = 0; e < 4; ++e) {
            int c = 16 * ct + 4 * g + e;
            size_t idx = (size_t)c * NN + i;
            ob[idx] = gm * (acc[ct][e] * rl) + xb[idx];
        }
}

// ---------------------------------------------------------------------------
extern "C" void kernel_launch(void* const* d_in, const int* in_sizes, int n_in,
                              void* d_out, int out_size, void* d_ws, size_t ws_size,
                              hipStream_t stream) {
    const float* x = (const float*)d_in[0];
    const float* Wq = (const float*)d_in[1];
    const float* bq = (const float*)d_in[2];
    const float* Wk = (const float*)d_in[3];
    const float* bk = (const float*)d_in[4];
    const float* Wv = (const float*)d_in[5];
    const float* bv = (const float*)d_in[6];
    const float* gamma = (const float*)d_in[7];
    float* out = (float*)d_out;

    // workspace layout (bytes):
    // q64 @0 (4MB) | k64 @4MB (4MB) | vC @8MB (16MB) | WcatT @24MB | bcat
    unsigned short* ws16 = (unsigned short*)d_ws;
    unsigned short* q64w = ws16;
    unsigned short* k64w = ws16 + 2097152;
    unsigned short* vCw = ws16 + 4194304;
    float* WcatT = (float*)((char*)d_ws + 25165824);
    float* bcat = WcatT + 81920;

    prep_w_kernel<<<320, 256, 0, stream>>>(Wq, bq, Wk, bk, Wv, bv, WcatT, bcat);
    qkv_kernel<<<BB * (NN / 64), 256, 0, stream>>>(x, WcatT, bcat, q64w, k64w, vCw);
    attn_kernel<<<512, 256, 0, stream>>>(q64w, k64w, vCw, x, gamma, out);
}